// Round 1
// baseline (2271.488 us; speedup 1.0000x reference)
//
#include <hip/hip_runtime.h>
#include <math.h>

#define NN 4096
#define CD 768
#define HD 512
#define OD 50
#define FGD 818   // CD + OD

// ---------------------------------------------------------------------------
// K1: sim = x @ x^T, fp32 inputs, fp64 accumulation (exact products).
// Upper-triangular blocks only; mirror-write the symmetric half.
// 64x64 tile, 16x16 threads, 4x4 per thread, K-tile 16.
// ---------------------------------------------------------------------------
__global__ __launch_bounds__(256) void sim_kernel(const float* __restrict__ x,
                                                  double* __restrict__ sim) {
    int bx = blockIdx.x, by = blockIdx.y;     // bx = col block, by = row block
    if (bx < by) return;                      // compute upper triangle only
    __shared__ double As[64][17];
    __shared__ double Bs[64][17];
    int tx = threadIdx.x, ty = threadIdx.y;
    int tid = ty * 16 + tx;
    int row0 = by * 64, col0 = bx * 64;
    double acc[4][4] = {};
    for (int k0 = 0; k0 < CD; k0 += 16) {
#pragma unroll
        for (int r = 0; r < 4; ++r) {
            int idx = tid + r * 256;
            int rr = idx >> 4, cc = idx & 15;
            As[rr][cc] = (double)x[(size_t)(row0 + rr) * CD + k0 + cc];
            Bs[rr][cc] = (double)x[(size_t)(col0 + rr) * CD + k0 + cc];
        }
        __syncthreads();
#pragma unroll
        for (int kk = 0; kk < 16; ++kk) {
            double a[4], b[4];
#pragma unroll
            for (int d = 0; d < 4; ++d) a[d] = As[ty * 4 + d][kk];
#pragma unroll
            for (int d = 0; d < 4; ++d) b[d] = Bs[tx * 4 + d][kk];
#pragma unroll
            for (int i = 0; i < 4; ++i)
#pragma unroll
                for (int j = 0; j < 4; ++j) acc[i][j] += a[i] * b[j];
        }
        __syncthreads();
    }
#pragma unroll
    for (int i = 0; i < 4; ++i)
#pragma unroll
        for (int j = 0; j < 4; ++j) {
            int r = row0 + ty * 4 + i, c = col0 + tx * 4 + j;
            sim[(size_t)r * NN + c] = acc[i][j];
            sim[(size_t)c * NN + r] = acc[i][j];   // symmetric mirror (exact same value)
        }
}

// ---------------------------------------------------------------------------
// K2: s = sum(sim over cross-label ordered pairs), cnt = #pairs, fp64.
// ---------------------------------------------------------------------------
__global__ __launch_bounds__(256) void thr_reduce(const double* __restrict__ sim,
                                                  const int* __restrict__ labels,
                                                  double* __restrict__ scal) {
    double s = 0.0, c = 0.0;
    size_t total = (size_t)NN * NN;
    for (size_t idx = (size_t)blockIdx.x * blockDim.x + threadIdx.x; idx < total;
         idx += (size_t)gridDim.x * blockDim.x) {
        int i = (int)(idx >> 12);
        int j = (int)(idx & (NN - 1));
        if (labels[i] != labels[j]) { s += sim[idx]; c += 1.0; }
    }
    for (int off = 32; off; off >>= 1) {
        s += __shfl_down(s, off);
        c += __shfl_down(c, off);
    }
    __shared__ double ss[4], cs[4];
    int wid = threadIdx.x >> 6, lane = threadIdx.x & 63;
    if (lane == 0) { ss[wid] = s; cs[wid] = c; }
    __syncthreads();
    if (threadIdx.x == 0) {
        double S = ss[0] + ss[1] + ss[2] + ss[3];
        double Cc = cs[0] + cs[1] + cs[2] + cs[3];
        atomicAdd(&scal[0], S);
        atomicAdd(&scal[1], Cc);
    }
}

// ---------------------------------------------------------------------------
// K3: per-row mask pass. Writes loss_mask (float 0/1) into d_out, adjacency
// a = edge|diag (fp32 0/1) into ws, and deg[i] = 1 + row edge count.
// One block per row; block-level reduction, no atomics.
// ---------------------------------------------------------------------------
__global__ __launch_bounds__(256) void mask_kernel(const double* __restrict__ sim,
                                                   const int* __restrict__ labels,
                                                   const double* __restrict__ scal,
                                                   float* __restrict__ a,
                                                   float* __restrict__ lm,
                                                   int* __restrict__ deg) {
    int i = blockIdx.x;
    int li = labels[i];
    double cnt = scal[1];
    double thr = (cnt > 0.0) ? (scal[0] / cnt) : 0.0;
    int count = 0;
    for (int j = threadIdx.x; j < NN; j += 256) {
        bool edge = (j != i) && (labels[j] == li) && (sim[(size_t)i * NN + j] <= thr);
        count += edge ? 1 : 0;
        a[(size_t)i * NN + j] = (j == i) ? 1.0f : (edge ? 1.0f : 0.0f);
        lm[(size_t)i * NN + j] = (edge && (i < j)) ? 1.0f : 0.0f;
    }
    for (int off = 32; off; off >>= 1) count += __shfl_down(count, off);
    __shared__ int cw[4];
    int wid = threadIdx.x >> 6, lane = threadIdx.x & 63;
    if (lane == 0) cw[wid] = count;
    __syncthreads();
    if (threadIdx.x == 0) deg[i] = 1 + cw[0] + cw[1] + cw[2] + cw[3];
}

__global__ void dinv_kernel(const int* __restrict__ deg, float* __restrict__ dinv) {
    int i = blockIdx.x * blockDim.x + threadIdx.x;
    if (i < NN) dinv[i] = (float)(1.0 / sqrt((double)deg[i]));
}

// ---------------------------------------------------------------------------
// Generic fp32 GEMM: C[r, c] = epi( rowscale[r] * sum_k A[r,k]*B[k,c] + bias[c] )
// A: MxK row-major, B: KxN row-major, C has leading dim ldc.
// 64x64 tile, 16x16 threads, 4x4 per thread, K-tile 16. K must be %16, M %64.
// ---------------------------------------------------------------------------
template <bool RELU, bool HASBIAS>
__global__ __launch_bounds__(256) void gemm_rs(const float* __restrict__ A,
                                               const float* __restrict__ B,
                                               float* __restrict__ C, int M, int Nn,
                                               int K, int ldc,
                                               const float* __restrict__ rowscale,
                                               const float* __restrict__ bias) {
    __shared__ float As[64][17];
    __shared__ float Bs[16][65];
    int tx = threadIdx.x, ty = threadIdx.y;
    int tid = ty * 16 + tx;
    int row0 = blockIdx.y * 64, n0 = blockIdx.x * 64;
    float acc[4][4] = {};
    for (int k0 = 0; k0 < K; k0 += 16) {
#pragma unroll
        for (int r = 0; r < 4; ++r) {
            int idx = tid + r * 256;
            {   // A tile: 64 rows x 16 k
                int rr = idx >> 4, cc = idx & 15;
                As[rr][cc] = A[(size_t)(row0 + rr) * K + k0 + cc];
            }
            {   // B tile: 16 k x 64 cols (guard cols)
                int rr = idx >> 6, cc = idx & 63;
                int col = n0 + cc;
                Bs[rr][cc] = (col < Nn) ? B[(size_t)(k0 + rr) * Nn + col] : 0.0f;
            }
        }
        __syncthreads();
#pragma unroll
        for (int kk = 0; kk < 16; ++kk) {
            float av[4], bv[4];
#pragma unroll
            for (int d = 0; d < 4; ++d) av[d] = As[ty * 4 + d][kk];
#pragma unroll
            for (int d = 0; d < 4; ++d) bv[d] = Bs[kk][tx * 4 + d];
#pragma unroll
            for (int i = 0; i < 4; ++i)
#pragma unroll
                for (int j = 0; j < 4; ++j) acc[i][j] += av[i] * bv[j];
        }
        __syncthreads();
    }
#pragma unroll
    for (int i = 0; i < 4; ++i) {
        int r = row0 + ty * 4 + i;
        float rs = rowscale ? rowscale[r] : 1.0f;
#pragma unroll
        for (int j = 0; j < 4; ++j) {
            int c = n0 + tx * 4 + j;
            if (c < Nn) {
                float v = acc[i][j] * rs;
                if (HASBIAS) v += bias[c];
                if (RELU) v = fmaxf(v, 0.0f);
                C[(size_t)r * ldc + c] = v;
            }
        }
    }
}

// ---------------------------------------------------------------------------
// Copy x into f_g[:, 0:768] and into the x output region.
// ---------------------------------------------------------------------------
__global__ __launch_bounds__(256) void copy_x(const float* __restrict__ x,
                                              float* __restrict__ fg,
                                              float* __restrict__ xo) {
    size_t total = (size_t)NN * CD;
    for (size_t idx = (size_t)blockIdx.x * blockDim.x + threadIdx.x; idx < total;
         idx += (size_t)gridDim.x * blockDim.x) {
        size_t i = idx / CD, c = idx - i * CD;
        float v = x[idx];
        fg[i * FGD + c] = v;
        xo[idx] = v;
    }
}

// ---------------------------------------------------------------------------
// out[i] = f_g[i,:] . fcW + fcb   (one block per row)
// ---------------------------------------------------------------------------
__global__ __launch_bounds__(256) void out_kernel(const float* __restrict__ fg,
                                                  const float* __restrict__ fcW,
                                                  const float* __restrict__ fcb,
                                                  float* __restrict__ out) {
    int i = blockIdx.x;
    float s = 0.0f;
    for (int j = threadIdx.x; j < FGD; j += 256)
        s += fg[(size_t)i * FGD + j] * fcW[j];
    for (int off = 32; off; off >>= 1) s += __shfl_down(s, off);
    __shared__ float sw[4];
    int wid = threadIdx.x >> 6, lane = threadIdx.x & 63;
    if (lane == 0) sw[wid] = s;
    __syncthreads();
    if (threadIdx.x == 0) out[i] = sw[0] + sw[1] + sw[2] + sw[3] + fcb[0];
}

extern "C" void kernel_launch(void* const* d_in, const int* in_sizes, int n_in,
                              void* d_out, int out_size, void* d_ws, size_t ws_size,
                              hipStream_t stream) {
    const float* x = (const float*)d_in[0];
    const int* labels = (const int*)d_in[1];
    const float* W1 = (const float*)d_in[2];
    const float* b1 = (const float*)d_in[3];
    const float* W2 = (const float*)d_in[4];
    const float* b2 = (const float*)d_in[5];
    const float* fcW = (const float*)d_in[6];
    const float* fcb = (const float*)d_in[7];
    float* outp = (float*)d_out;

    // d_out layout (flat fp32): out[4096] | f_g[4096*818] | loss_mask[4096*4096] | x[4096*768]
    const size_t o_out = 0;
    const size_t o_fg = 4096;
    const size_t o_lm = o_fg + (size_t)NN * FGD;
    const size_t o_x = o_lm + (size_t)NN * NN;

    // workspace layout
    char* ws = (char*)d_ws;
    double* sim = (double*)ws;                                   // 128 MiB
    float* a = (float*)(ws + (size_t)NN * NN * 8);               // 64 MiB
    float* xw1s = (float*)(ws + (size_t)NN * NN * 12);           // 8 MiB
    float* h = (float*)((char*)xw1s + (size_t)NN * HD * 4);      // 8 MiB
    float* hw2s = (float*)((char*)h + (size_t)NN * HD * 4);      // 0.8 MiB
    int* deg = (int*)((char*)hw2s + (size_t)NN * OD * 4);
    float* dinv = (float*)((char*)deg + (size_t)NN * 4);
    double* scal = (double*)((char*)dinv + (size_t)NN * 4);      // s, cnt

    // zero the reduction scalars (ws is poisoned 0xAA before every launch)
    hipMemsetAsync(scal, 0, 2 * sizeof(double), stream);

    dim3 b16(16, 16);

    // K1: sim = x @ x^T (fp64 accum, upper triangle + mirror)
    sim_kernel<<<dim3(64, 64), b16, 0, stream>>>(x, sim);

    // K2: threshold sums
    thr_reduce<<<2048, 256, 0, stream>>>(sim, labels, scal);

    // K3: mask + adjacency + degrees (loss_mask written into d_out)
    mask_kernel<<<NN, 256, 0, stream>>>(sim, labels, scal, a, outp + o_lm, deg);
    dinv_kernel<<<(NN + 255) / 256, 256, 0, stream>>>(deg, dinv);

    // K4: xw1s = dinv ⊙ (x @ W1)      [4096x512, K=768]
    gemm_rs<false, false><<<dim3(HD / 64, NN / 64), b16, 0, stream>>>(
        x, W1, xw1s, NN, HD, CD, HD, dinv, nullptr);

    // K5: h = relu(dinv ⊙ (a @ xw1s) + b1)   [4096x512, K=4096]
    gemm_rs<true, true><<<dim3(HD / 64, NN / 64), b16, 0, stream>>>(
        a, xw1s, h, NN, HD, NN, HD, dinv, b1);

    // K6: hw2s = dinv ⊙ (h @ W2)      [4096x50, K=512]
    gemm_rs<false, false><<<dim3(1, NN / 64), b16, 0, stream>>>(
        h, W2, hw2s, NN, OD, HD, OD, dinv, nullptr);

    // K7: g = dinv ⊙ (a @ hw2s) + b2  -> written into f_g[:, 768:818]
    gemm_rs<false, true><<<dim3(1, NN / 64), b16, 0, stream>>>(
        a, hw2s, outp + o_fg + CD, NN, OD, NN, FGD, dinv, b2);

    // copy x into f_g[:, 0:768] and the x output
    copy_x<<<8192, 256, 0, stream>>>(x, outp + o_fg, outp + o_x);

    // out = f_g @ fcW + fcb
    out_kernel<<<NN, 256, 0, stream>>>(outp + o_fg, fcW, fcb, outp + o_out);
}

// Round 3
// 1708.102 us; speedup vs baseline: 1.3298x; 1.3298x over previous
//
#include <hip/hip_runtime.h>
#include <math.h>

#define NN 4096
#define CD 768
#define HD 512
#define OD 50
#define FGD 818   // CD + OD

typedef double v4d __attribute__((ext_vector_type(4)));

// ---------------------------------------------------------------------------
// K1: sim = x @ x^T via fp64 MFMA (v_mfma_f64_16x16x4_f64).
// fp32 inputs staged in LDS as fp32, converted to fp64 at fragment load
// (products exact in fp64). Upper-triangular blocks only; mirror half via
// LDS transpose. The C/D register->(row,col) mapping is DISCOVERED AT
// RUNTIME with two probe MFMAs, so the store is correct under any operand
// orientation / accumulator permutation the hardware uses.
// Block = 256 threads (4 waves), 64x64 tile; wave w -> 32x32 subtile.
// ---------------------------------------------------------------------------
__global__ __launch_bounds__(256) void sim_mfma(const float* __restrict__ x,
                                                double* __restrict__ sim) {
    int bx = blockIdx.x, by = blockIdx.y;   // bx = col block, by = row block
    if (bx < by) return;                    // upper triangle only
    __shared__ double smemd[64 * 65];       // 33280 B; staging then transpose
    float* XrF = (float*)smemd;             // [64][36] floats
    float* XcF = XrF + 64 * 36;             // [64][36] floats
    int tid = threadIdx.x;
    int lane = tid & 63;
    int w = tid >> 6;
    int wr = w >> 1, wc = w & 1;            // wave's 32x32 subtile coords
    int row0 = by * 64, col0 = bx * 64;
    int m = lane & 15, kf = lane >> 4;      // fragment indices (quad = k-group)

    // ---- runtime C/D layout probe ----
    // D(lane,r) = sum_k op1row[P(lane,r)][k] * op2row[Q(lane,r)][k]
    // probe1: op1 value = row-id, op2 selects k==0  -> pr[r] = P
    // probe2: swapped                               -> pc[r] = Q
    v4d zed = {0.0, 0.0, 0.0, 0.0};
    double idv = (double)m;
    double sel = (kf == 0) ? 1.0 : 0.0;
    v4d pr = __builtin_amdgcn_mfma_f64_16x16x4f64(idv, sel, zed, 0, 0, 0);
    v4d pc = __builtin_amdgcn_mfma_f64_16x16x4f64(sel, idv, zed, 0, 0, 0);
    int prow[4], pcol[4];
#pragma unroll
    for (int r = 0; r < 4; ++r) { prow[r] = (int)pr[r]; pcol[r] = (int)pc[r]; }

    v4d acc[2][2] = {{{0.0, 0.0, 0.0, 0.0}, {0.0, 0.0, 0.0, 0.0}},
                     {{0.0, 0.0, 0.0, 0.0}, {0.0, 0.0, 0.0, 0.0}}};

    for (int k0 = 0; k0 < CD; k0 += 32) {
        // stage 64x32 fp32 tiles (float4; pitch 36 floats = 144 B, 16B-aligned)
#pragma unroll
        for (int t = 0; t < 2; ++t) {
            int id2 = tid + t * 256;
            int row = id2 >> 3, f4 = id2 & 7;
            *(float4*)&XrF[row * 36 + f4 * 4] =
                *(const float4*)&x[(size_t)(row0 + row) * CD + k0 + f4 * 4];
            *(float4*)&XcF[row * 36 + f4 * 4] =
                *(const float4*)&x[(size_t)(col0 + row) * CD + k0 + f4 * 4];
        }
        __syncthreads();
#pragma unroll
        for (int kk = 0; kk < 8; ++kk) {    // 8 k-steps of 4
            double A0 = (double)XrF[(wr * 32 + m) * 36 + kk * 4 + kf];
            double A1 = (double)XrF[(wr * 32 + 16 + m) * 36 + kk * 4 + kf];
            double B0 = (double)XcF[(wc * 32 + m) * 36 + kk * 4 + kf];
            double B1 = (double)XcF[(wc * 32 + 16 + m) * 36 + kk * 4 + kf];
            acc[0][0] = __builtin_amdgcn_mfma_f64_16x16x4f64(A0, B0, acc[0][0], 0, 0, 0);
            acc[0][1] = __builtin_amdgcn_mfma_f64_16x16x4f64(A0, B1, acc[0][1], 0, 0, 0);
            acc[1][0] = __builtin_amdgcn_mfma_f64_16x16x4f64(A1, B0, acc[1][0], 0, 0, 0);
            acc[1][1] = __builtin_amdgcn_mfma_f64_16x16x4f64(A1, B1, acc[1][1], 0, 0, 0);
        }
        __syncthreads();
    }

    // acc[i][j][r] = sim_tile[wr*32 + i*16 + prow[r]][wc*32 + j*16 + pcol[r]]
    // direct (row-major) write
#pragma unroll
    for (int i = 0; i < 2; ++i)
#pragma unroll
        for (int j = 0; j < 2; ++j) {
            int rbase = wr * 32 + i * 16, cbase = wc * 32 + j * 16;
#pragma unroll
            for (int r = 0; r < 4; ++r) {
                sim[(size_t)(row0 + rbase + prow[r]) * NN + col0 + cbase + pcol[r]] =
                    acc[i][j][r];
            }
        }
    // mirror write via LDS transpose (coalesced rows of the transposed tile)
    __syncthreads();
    double* T = smemd;                      // [64][65]
#pragma unroll
    for (int i = 0; i < 2; ++i)
#pragma unroll
        for (int j = 0; j < 2; ++j) {
            int rbase = wr * 32 + i * 16, cbase = wc * 32 + j * 16;
#pragma unroll
            for (int r = 0; r < 4; ++r) {
                T[(cbase + pcol[r]) * 65 + rbase + prow[r]] = acc[i][j][r];
            }
        }
    __syncthreads();
    for (int t = tid; t < 4096; t += 256) {
        int cc = t >> 6, rr = t & 63;
        sim[(size_t)(col0 + cc) * NN + row0 + rr] = T[cc * 65 + rr];
    }
}

// ---------------------------------------------------------------------------
// K2: s = sum(sim over cross-label ordered pairs), cnt = #pairs, fp64.
// ---------------------------------------------------------------------------
__global__ __launch_bounds__(256) void thr_reduce(const double* __restrict__ sim,
                                                  const int* __restrict__ labels,
                                                  double* __restrict__ scal) {
    double s = 0.0, c = 0.0;
    size_t total = (size_t)NN * NN;
    for (size_t idx = (size_t)blockIdx.x * blockDim.x + threadIdx.x; idx < total;
         idx += (size_t)gridDim.x * blockDim.x) {
        int i = (int)(idx >> 12);
        int j = (int)(idx & (NN - 1));
        if (labels[i] != labels[j]) { s += sim[idx]; c += 1.0; }
    }
    for (int off = 32; off; off >>= 1) {
        s += __shfl_down(s, off);
        c += __shfl_down(c, off);
    }
    __shared__ double ss[4], cs[4];
    int wid = threadIdx.x >> 6, lane = threadIdx.x & 63;
    if (lane == 0) { ss[wid] = s; cs[wid] = c; }
    __syncthreads();
    if (threadIdx.x == 0) {
        double S = ss[0] + ss[1] + ss[2] + ss[3];
        double Cc = cs[0] + cs[1] + cs[2] + cs[3];
        atomicAdd(&scal[0], S);
        atomicAdd(&scal[1], Cc);
    }
}

// ---------------------------------------------------------------------------
// K3: per-row mask pass. loss_mask (0/1) -> d_out, adjacency a -> ws, deg.
// ---------------------------------------------------------------------------
__global__ __launch_bounds__(256) void mask_kernel(const double* __restrict__ sim,
                                                   const int* __restrict__ labels,
                                                   const double* __restrict__ scal,
                                                   float* __restrict__ a,
                                                   float* __restrict__ lm,
                                                   int* __restrict__ deg) {
    int i = blockIdx.x;
    int li = labels[i];
    double cnt = scal[1];
    double thr = (cnt > 0.0) ? (scal[0] / cnt) : 0.0;
    int count = 0;
    for (int j = threadIdx.x; j < NN; j += 256) {
        bool edge = (j != i) && (labels[j] == li) && (sim[(size_t)i * NN + j] <= thr);
        count += edge ? 1 : 0;
        a[(size_t)i * NN + j] = (j == i) ? 1.0f : (edge ? 1.0f : 0.0f);
        lm[(size_t)i * NN + j] = (edge && (i < j)) ? 1.0f : 0.0f;
    }
    for (int off = 32; off; off >>= 1) count += __shfl_down(count, off);
    __shared__ int cw[4];
    int wid = threadIdx.x >> 6, lane = threadIdx.x & 63;
    if (lane == 0) cw[wid] = count;
    __syncthreads();
    if (threadIdx.x == 0) deg[i] = 1 + cw[0] + cw[1] + cw[2] + cw[3];
}

__global__ void dinv_kernel(const int* __restrict__ deg, float* __restrict__ dinv) {
    int i = blockIdx.x * blockDim.x + threadIdx.x;
    if (i < NN) dinv[i] = (float)(1.0 / sqrt((double)deg[i]));
}

// ---------------------------------------------------------------------------
// Generic fp32 GEMM: C[r, c] = epi( rowscale[r] * sum_k A[r,k]*B[k,c] + bias[c] )
// ---------------------------------------------------------------------------
template <bool RELU, bool HASBIAS>
__global__ __launch_bounds__(256) void gemm_rs(const float* __restrict__ A,
                                               const float* __restrict__ B,
                                               float* __restrict__ C, int M, int Nn,
                                               int K, int ldc,
                                               const float* __restrict__ rowscale,
                                               const float* __restrict__ bias) {
    __shared__ float As[64][17];
    __shared__ float Bs[16][65];
    int tx = threadIdx.x, ty = threadIdx.y;
    int tid = ty * 16 + tx;
    int row0 = blockIdx.y * 64, n0 = blockIdx.x * 64;
    float acc[4][4] = {};
    for (int k0 = 0; k0 < K; k0 += 16) {
#pragma unroll
        for (int r = 0; r < 4; ++r) {
            int idx = tid + r * 256;
            {
                int rr = idx >> 4, cc = idx & 15;
                As[rr][cc] = A[(size_t)(row0 + rr) * K + k0 + cc];
            }
            {
                int rr = idx >> 6, cc = idx & 63;
                int col = n0 + cc;
                Bs[rr][cc] = (col < Nn) ? B[(size_t)(k0 + rr) * Nn + col] : 0.0f;
            }
        }
        __syncthreads();
#pragma unroll
        for (int kk = 0; kk < 16; ++kk) {
            float av[4], bv[4];
#pragma unroll
            for (int d = 0; d < 4; ++d) av[d] = As[ty * 4 + d][kk];
#pragma unroll
            for (int d = 0; d < 4; ++d) bv[d] = Bs[kk][tx * 4 + d];
#pragma unroll
            for (int i = 0; i < 4; ++i)
#pragma unroll
                for (int j = 0; j < 4; ++j) acc[i][j] += av[i] * bv[j];
        }
        __syncthreads();
    }
#pragma unroll
    for (int i = 0; i < 4; ++i) {
        int r = row0 + ty * 4 + i;
        float rs = rowscale ? rowscale[r] : 1.0f;
#pragma unroll
        for (int j = 0; j < 4; ++j) {
            int c = n0 + tx * 4 + j;
            if (c < Nn) {
                float v = acc[i][j] * rs;
                if (HASBIAS) v += bias[c];
                if (RELU) v = fmaxf(v, 0.0f);
                C[(size_t)r * ldc + c] = v;
            }
        }
    }
}

// ---------------------------------------------------------------------------
// Copy x into f_g[:, 0:768] and into the x output region.
// ---------------------------------------------------------------------------
__global__ __launch_bounds__(256) void copy_x(const float* __restrict__ x,
                                              float* __restrict__ fg,
                                              float* __restrict__ xo) {
    size_t total = (size_t)NN * CD;
    for (size_t idx = (size_t)blockIdx.x * blockDim.x + threadIdx.x; idx < total;
         idx += (size_t)gridDim.x * blockDim.x) {
        size_t i = idx / CD, c = idx - i * CD;
        float v = x[idx];
        fg[i * FGD + c] = v;
        xo[idx] = v;
    }
}

// ---------------------------------------------------------------------------
// out[i] = f_g[i,:] . fcW + fcb   (one block per row)
// ---------------------------------------------------------------------------
__global__ __launch_bounds__(256) void out_kernel(const float* __restrict__ fg,
                                                  const float* __restrict__ fcW,
                                                  const float* __restrict__ fcb,
                                                  float* __restrict__ out) {
    int i = blockIdx.x;
    float s = 0.0f;
    for (int j = threadIdx.x; j < FGD; j += 256)
        s += fg[(size_t)i * FGD + j] * fcW[j];
    for (int off = 32; off; off >>= 1) s += __shfl_down(s, off);
    __shared__ float sw[4];
    int wid = threadIdx.x >> 6, lane = threadIdx.x & 63;
    if (lane == 0) sw[wid] = s;
    __syncthreads();
    if (threadIdx.x == 0) out[i] = sw[0] + sw[1] + sw[2] + sw[3] + fcb[0];
}

extern "C" void kernel_launch(void* const* d_in, const int* in_sizes, int n_in,
                              void* d_out, int out_size, void* d_ws, size_t ws_size,
                              hipStream_t stream) {
    const float* x = (const float*)d_in[0];
    const int* labels = (const int*)d_in[1];
    const float* W1 = (const float*)d_in[2];
    const float* b1 = (const float*)d_in[3];
    const float* W2 = (const float*)d_in[4];
    const float* b2 = (const float*)d_in[5];
    const float* fcW = (const float*)d_in[6];
    const float* fcb = (const float*)d_in[7];
    float* outp = (float*)d_out;

    // d_out layout (flat fp32): out[4096] | f_g[4096*818] | loss_mask[4096*4096] | x[4096*768]
    const size_t o_out = 0;
    const size_t o_fg = 4096;
    const size_t o_lm = o_fg + (size_t)NN * FGD;
    const size_t o_x = o_lm + (size_t)NN * NN;

    // workspace layout
    char* ws = (char*)d_ws;
    double* sim = (double*)ws;                                   // 128 MiB
    float* a = (float*)(ws + (size_t)NN * NN * 8);               // 64 MiB
    float* xw1s = (float*)(ws + (size_t)NN * NN * 12);           // 8 MiB
    float* h = (float*)((char*)xw1s + (size_t)NN * HD * 4);      // 8 MiB
    float* hw2s = (float*)((char*)h + (size_t)NN * HD * 4);      // 0.8 MiB
    int* deg = (int*)((char*)hw2s + (size_t)NN * OD * 4);
    float* dinv = (float*)((char*)deg + (size_t)NN * 4);
    double* scal = (double*)((char*)dinv + (size_t)NN * 4);      // s, cnt

    hipMemsetAsync(scal, 0, 2 * sizeof(double), stream);

    dim3 b16(16, 16);

    // K1: sim = x @ x^T (fp64 MFMA, runtime-probed C/D layout)
    sim_mfma<<<dim3(64, 64), 256, 0, stream>>>(x, sim);

    // K2: threshold sums
    thr_reduce<<<2048, 256, 0, stream>>>(sim, labels, scal);

    // K3: mask + adjacency + degrees
    mask_kernel<<<NN, 256, 0, stream>>>(sim, labels, scal, a, outp + o_lm, deg);
    dinv_kernel<<<(NN + 255) / 256, 256, 0, stream>>>(deg, dinv);

    // K4: xw1s = dinv ⊙ (x @ W1)      [4096x512, K=768]
    gemm_rs<false, false><<<dim3(HD / 64, NN / 64), b16, 0, stream>>>(
        x, W1, xw1s, NN, HD, CD, HD, dinv, nullptr);

    // K5: h = relu(dinv ⊙ (a @ xw1s) + b1)   [4096x512, K=4096]
    gemm_rs<true, true><<<dim3(HD / 64, NN / 64), b16, 0, stream>>>(
        a, xw1s, h, NN, HD, NN, HD, dinv, b1);

    // K6: hw2s = dinv ⊙ (h @ W2)      [4096x50, K=512]
    gemm_rs<false, false><<<dim3(1, NN / 64), b16, 0, stream>>>(
        h, W2, hw2s, NN, OD, HD, OD, dinv, nullptr);

    // K7: g = dinv ⊙ (a @ hw2s) + b2  -> f_g[:, 768:818]
    gemm_rs<false, true><<<dim3(1, NN / 64), b16, 0, stream>>>(
        a, hw2s, outp + o_fg + CD, NN, OD, NN, FGD, dinv, b2);

    copy_x<<<8192, 256, 0, stream>>>(x, outp + o_fg, outp + o_x);

    out_kernel<<<NN, 256, 0, stream>>>(outp + o_fg, fcW, fcb, outp + o_out);
}

// Round 5
// 723.828 us; speedup vs baseline: 3.1382x; 2.3598x over previous
//
#include <hip/hip_runtime.h>
#include <hip/hip_bf16.h>
#include <math.h>

#define NN 4096
#define CD 768
#define HD 512
#define OD 50
#define FGD 818   // CD + OD

typedef double v4d __attribute__((ext_vector_type(4)));
typedef short short8 __attribute__((ext_vector_type(8)));
typedef float f32x4 __attribute__((ext_vector_type(4)));
typedef unsigned short ushortT;

__device__ inline ushortT f2bf(float v) {
    __hip_bfloat16 b = __float2bfloat16(v);
    return *(ushortT*)&b;
}
__device__ inline float bf2f(ushortT u) {
    __hip_bfloat16 b = *(__hip_bfloat16*)&u;
    return __bfloat162float(b);
}

// ---------------------------------------------------------------------------
// K1: sim = x @ x^T via fp64 MFMA, runtime-probed C/D layout (verified R3).
// ---------------------------------------------------------------------------
__global__ __launch_bounds__(256) void sim_mfma(const float* __restrict__ x,
                                                double* __restrict__ sim) {
    int bx = blockIdx.x, by = blockIdx.y;
    if (bx < by) return;                    // upper triangle only
    __shared__ double smemd[64 * 65];
    float* XrF = (float*)smemd;             // [64][36]
    float* XcF = XrF + 64 * 36;
    int tid = threadIdx.x;
    int lane = tid & 63;
    int w = tid >> 6;
    int wr = w >> 1, wc = w & 1;
    int row0 = by * 64, col0 = bx * 64;
    int m = lane & 15, kf = lane >> 4;

    v4d zed = {0.0, 0.0, 0.0, 0.0};
    double idv = (double)m;
    double sel = (kf == 0) ? 1.0 : 0.0;
    v4d pr = __builtin_amdgcn_mfma_f64_16x16x4f64(idv, sel, zed, 0, 0, 0);
    v4d pc = __builtin_amdgcn_mfma_f64_16x16x4f64(sel, idv, zed, 0, 0, 0);
    int prow[4], pcol[4];
#pragma unroll
    for (int r = 0; r < 4; ++r) { prow[r] = (int)pr[r]; pcol[r] = (int)pc[r]; }

    v4d acc[2][2] = {{{0.0, 0.0, 0.0, 0.0}, {0.0, 0.0, 0.0, 0.0}},
                     {{0.0, 0.0, 0.0, 0.0}, {0.0, 0.0, 0.0, 0.0}}};

    for (int k0 = 0; k0 < CD; k0 += 32) {
#pragma unroll
        for (int t = 0; t < 2; ++t) {
            int id2 = tid + t * 256;
            int row = id2 >> 3, f4 = id2 & 7;
            *(float4*)&XrF[row * 36 + f4 * 4] =
                *(const float4*)&x[(size_t)(row0 + row) * CD + k0 + f4 * 4];
            *(float4*)&XcF[row * 36 + f4 * 4] =
                *(const float4*)&x[(size_t)(col0 + row) * CD + k0 + f4 * 4];
        }
        __syncthreads();
#pragma unroll
        for (int kk = 0; kk < 8; ++kk) {
            double A0 = (double)XrF[(wr * 32 + m) * 36 + kk * 4 + kf];
            double A1 = (double)XrF[(wr * 32 + 16 + m) * 36 + kk * 4 + kf];
            double B0 = (double)XcF[(wc * 32 + m) * 36 + kk * 4 + kf];
            double B1 = (double)XcF[(wc * 32 + 16 + m) * 36 + kk * 4 + kf];
            acc[0][0] = __builtin_amdgcn_mfma_f64_16x16x4f64(A0, B0, acc[0][0], 0, 0, 0);
            acc[0][1] = __builtin_amdgcn_mfma_f64_16x16x4f64(A0, B1, acc[0][1], 0, 0, 0);
            acc[1][0] = __builtin_amdgcn_mfma_f64_16x16x4f64(A1, B0, acc[1][0], 0, 0, 0);
            acc[1][1] = __builtin_amdgcn_mfma_f64_16x16x4f64(A1, B1, acc[1][1], 0, 0, 0);
        }
        __syncthreads();
    }

#pragma unroll
    for (int i = 0; i < 2; ++i)
#pragma unroll
        for (int j = 0; j < 2; ++j) {
            int rbase = wr * 32 + i * 16, cbase = wc * 32 + j * 16;
#pragma unroll
            for (int r = 0; r < 4; ++r) {
                sim[(size_t)(row0 + rbase + prow[r]) * NN + col0 + cbase + pcol[r]] =
                    acc[i][j][r];
            }
        }
    __syncthreads();
    double* T = smemd;
#pragma unroll
    for (int i = 0; i < 2; ++i)
#pragma unroll
        for (int j = 0; j < 2; ++j) {
            int rbase = wr * 32 + i * 16, cbase = wc * 32 + j * 16;
#pragma unroll
            for (int r = 0; r < 4; ++r) {
                T[(cbase + pcol[r]) * 65 + rbase + prow[r]] = acc[i][j][r];
            }
        }
    __syncthreads();
    for (int t = tid; t < 4096; t += 256) {
        int cc = t >> 6, rr = t & 63;
        sim[(size_t)(col0 + cc) * NN + row0 + rr] = T[cc * 65 + rr];
    }
}

// ---------------------------------------------------------------------------
// K2: threshold sums (fp64)
// ---------------------------------------------------------------------------
__global__ __launch_bounds__(256) void thr_reduce(const double* __restrict__ sim,
                                                  const int* __restrict__ labels,
                                                  double* __restrict__ scal) {
    double s = 0.0, c = 0.0;
    size_t total = (size_t)NN * NN;
    for (size_t idx = (size_t)blockIdx.x * blockDim.x + threadIdx.x; idx < total;
         idx += (size_t)gridDim.x * blockDim.x) {
        int i = (int)(idx >> 12);
        int j = (int)(idx & (NN - 1));
        if (labels[i] != labels[j]) { s += sim[idx]; c += 1.0; }
    }
    for (int off = 32; off; off >>= 1) {
        s += __shfl_down(s, off);
        c += __shfl_down(c, off);
    }
    __shared__ double ss[4], cs[4];
    int wid = threadIdx.x >> 6, lane = threadIdx.x & 63;
    if (lane == 0) { ss[wid] = s; cs[wid] = c; }
    __syncthreads();
    if (threadIdx.x == 0) {
        atomicAdd(&scal[0], ss[0] + ss[1] + ss[2] + ss[3]);
        atomicAdd(&scal[1], cs[0] + cs[1] + cs[2] + cs[3]);
    }
}

// ---------------------------------------------------------------------------
// K3: mask pass -> loss_mask (fp32, d_out), adjacency as bf16 (exact 0/1), deg
// ---------------------------------------------------------------------------
__global__ __launch_bounds__(256) void mask_kernel(const double* __restrict__ sim,
                                                   const int* __restrict__ labels,
                                                   const double* __restrict__ scal,
                                                   ushortT* __restrict__ ab,
                                                   float* __restrict__ lm,
                                                   int* __restrict__ deg) {
    int i = blockIdx.x;
    int li = labels[i];
    double cnt = scal[1];
    double thr = (cnt > 0.0) ? (scal[0] / cnt) : 0.0;
    int count = 0;
    for (int j = threadIdx.x; j < NN; j += 256) {
        bool edge = (j != i) && (labels[j] == li) && (sim[(size_t)i * NN + j] <= thr);
        count += edge ? 1 : 0;
        ab[(size_t)i * NN + j] = (j == i || edge) ? (ushortT)0x3F80 : (ushortT)0;
        lm[(size_t)i * NN + j] = (edge && (i < j)) ? 1.0f : 0.0f;
    }
    for (int off = 32; off; off >>= 1) count += __shfl_down(count, off);
    __shared__ int cw[4];
    int wid = threadIdx.x >> 6, lane = threadIdx.x & 63;
    if (lane == 0) cw[wid] = count;
    __syncthreads();
    if (threadIdx.x == 0) deg[i] = 1 + cw[0] + cw[1] + cw[2] + cw[3];
}

__global__ void dinv_kernel(const int* __restrict__ deg, float* __restrict__ dinv) {
    int i = blockIdx.x * blockDim.x + threadIdx.x;
    if (i < NN) dinv[i] = (float)(1.0 / sqrt((double)deg[i]));
}

// ---------------------------------------------------------------------------
// split fp32 row-major -> hi/lo bf16 planes (same layout)
// ---------------------------------------------------------------------------
__global__ __launch_bounds__(256) void split_rm(const float* __restrict__ X,
                                                ushortT* __restrict__ Xh,
                                                ushortT* __restrict__ Xl, size_t total) {
    for (size_t i = (size_t)blockIdx.x * blockDim.x + threadIdx.x; i < total;
         i += (size_t)gridDim.x * blockDim.x) {
        float v = X[i];
        ushortT h = f2bf(v);
        Xh[i] = h;
        Xl[i] = f2bf(v - bf2f(h));
    }
}

// ---------------------------------------------------------------------------
// transpose + split: P[K][N] fp32 -> Th/Tl[Npad][K] bf16 (rows n>=N zeroed)
// ---------------------------------------------------------------------------
__global__ __launch_bounds__(256) void transp_split(const float* __restrict__ P,
                                                    ushortT* __restrict__ Th,
                                                    ushortT* __restrict__ Tl,
                                                    int K, int N, int Npad) {
    __shared__ float t[32][33];
    int k0 = blockIdx.x * 32, n0 = blockIdx.y * 32;
    int tx = threadIdx.x & 31, ty = threadIdx.x >> 5;   // ty: 0..7
#pragma unroll
    for (int s = 0; s < 4; ++s) {
        int k = k0 + ty + s * 8, n = n0 + tx;
        t[ty + s * 8][tx] = (k < K && n < N) ? P[(size_t)k * N + n] : 0.0f;
    }
    __syncthreads();
#pragma unroll
    for (int s = 0; s < 4; ++s) {
        int n = n0 + ty + s * 8, k = k0 + tx;
        if (n < Npad && k < K) {
            float v = t[tx][ty + s * 8];
            ushortT h = f2bf(v);
            Th[(size_t)n * K + k] = h;
            Tl[(size_t)n * K + k] = f2bf(v - bf2f(h));
        }
    }
}

// ---------------------------------------------------------------------------
// Generic bf16-MFMA GEMM with hi/lo split operands.
// A planes: row-major M x K bf16. B planes: TRANSPOSED, [Npad][K] bf16.
// C = epi( rowscale[r] * (A@B) [+ bias] [relu] )
// EPI: 0 = fp32 to C (ldc), 1 = split bf16 row-major to Ch/Cl (ldc),
//      2 = split bf16 transposed to Ch/Cl ([Npad][M], via LDS transpose)
// Block 256 = 4 waves; 64x64 tile; wave -> 32x32 (2x2 frags of 16x16x32).
// M % 64 == 0, K % 64 == 0; B padded so (blockIdx.x+1)*64 <= Npad.
// ---------------------------------------------------------------------------
template <int ASPLIT, int BSPLIT, bool SKIP_LL, bool RELU, bool HASBIAS, int EPI>
__global__ __launch_bounds__(256) void gemm_mfma(
    const ushortT* __restrict__ A0, const ushortT* __restrict__ A1,
    const ushortT* __restrict__ B0, const ushortT* __restrict__ B1,
    float* __restrict__ C, ushortT* __restrict__ Ch, ushortT* __restrict__ Cl,
    int M, int Nn, int K, int ldc,
    const float* __restrict__ rowscale, const float* __restrict__ bias) {
    constexpr int NT = ASPLIT + BSPLIT;
    __shared__ ushortT lds[NT * 64 * 72];
    int tid = threadIdx.x;
    int lane = tid & 63;
    int w = tid >> 6;
    int wr = w >> 1, wc = w & 1;
    int m = lane & 15, quad = lane >> 4;
    int row0 = blockIdx.y * 64, col0 = blockIdx.x * 64;

    f32x4 acc[2][2] = {{{0.f, 0.f, 0.f, 0.f}, {0.f, 0.f, 0.f, 0.f}},
                       {{0.f, 0.f, 0.f, 0.f}, {0.f, 0.f, 0.f, 0.f}}};

    for (int k0 = 0; k0 < K; k0 += 64) {
        // stage 64 rows x 64 cols per plane: 512 short8 chunks -> 2 per thread
#pragma unroll
        for (int t = 0; t < 2; ++t) {
            int id2 = tid + t * 256;
            int row = id2 >> 3, c8 = (id2 & 7) * 8;
#pragma unroll
            for (int p = 0; p < ASPLIT; ++p) {
                const ushortT* Ap = (p == 0) ? A0 : A1;
                *(short8*)&lds[p * 4608 + row * 72 + c8] =
                    *(const short8*)&Ap[(size_t)(row0 + row) * K + k0 + c8];
            }
#pragma unroll
            for (int q = 0; q < BSPLIT; ++q) {
                const ushortT* Bq = (q == 0) ? B0 : B1;
                *(short8*)&lds[(ASPLIT + q) * 4608 + row * 72 + c8] =
                    *(const short8*)&Bq[(size_t)(col0 + row) * K + k0 + c8];
            }
        }
        __syncthreads();
#pragma unroll
        for (int ks = 0; ks < 2; ++ks) {
            short8 af[ASPLIT][2], bf[BSPLIT][2];
#pragma unroll
            for (int p = 0; p < ASPLIT; ++p)
#pragma unroll
                for (int i = 0; i < 2; ++i)
                    af[p][i] = *(const short8*)&lds[p * 4608 +
                                                    (wr * 32 + i * 16 + m) * 72 +
                                                    ks * 32 + quad * 8];
#pragma unroll
            for (int q = 0; q < BSPLIT; ++q)
#pragma unroll
                for (int j = 0; j < 2; ++j)
                    bf[q][j] = *(const short8*)&lds[(ASPLIT + q) * 4608 +
                                                    (wc * 32 + j * 16 + m) * 72 +
                                                    ks * 32 + quad * 8];
#pragma unroll
            for (int p = 0; p < ASPLIT; ++p)
#pragma unroll
                for (int q = 0; q < BSPLIT; ++q) {
                    if (SKIP_LL && p == 1 && q == 1) continue;
#pragma unroll
                    for (int i = 0; i < 2; ++i)
#pragma unroll
                        for (int j = 0; j < 2; ++j)
                            acc[i][j] = __builtin_amdgcn_mfma_f32_16x16x32_bf16(
                                af[p][i], bf[q][j], acc[i][j], 0, 0, 0);
                }
        }
        __syncthreads();
    }

    if (EPI == 2) {
        // transposed split output via LDS transpose (reuse staging LDS)
        ushortT* Th = lds;
        ushortT* Tl = lds + 4608;
#pragma unroll
        for (int i = 0; i < 2; ++i)
#pragma unroll
            for (int j = 0; j < 2; ++j) {
#pragma unroll
                for (int r = 0; r < 4; ++r) {
                    int row = wr * 32 + i * 16 + quad * 4 + r;
                    int col = wc * 32 + j * 16 + m;
                    float v = acc[i][j][r] * rowscale[row0 + row];
                    ushortT h = f2bf(v);
                    Th[col * 72 + row] = h;
                    Tl[col * 72 + row] = f2bf(v - bf2f(h));
                }
            }
        __syncthreads();
        // 64 cols x 64 rows per plane: 512 short8 chunks -> 2 per thread
#pragma unroll
        for (int t = 0; t < 2; ++t) {
            int id2 = tid + t * 256;
            int cc = id2 >> 3, chunk = id2 & 7;
            *(short8*)&Ch[(size_t)(col0 + cc) * M + row0 + chunk * 8] =
                *(const short8*)&Th[cc * 72 + chunk * 8];
            *(short8*)&Cl[(size_t)(col0 + cc) * M + row0 + chunk * 8] =
                *(const short8*)&Tl[cc * 72 + chunk * 8];
        }
    } else {
#pragma unroll
        for (int i = 0; i < 2; ++i)
#pragma unroll
            for (int j = 0; j < 2; ++j) {
#pragma unroll
                for (int r = 0; r < 4; ++r) {
                    int row = wr * 32 + i * 16 + quad * 4 + r;
                    int col = wc * 32 + j * 16 + m;
                    int gr = row0 + row, gc = col0 + col;
                    if (gc < Nn) {
                        float v = acc[i][j][r] * rowscale[gr];
                        if (HASBIAS) v += bias[gc];
                        if (RELU) v = fmaxf(v, 0.0f);
                        if (EPI == 0) {
                            C[(size_t)gr * ldc + gc] = v;
                        } else {
                            ushortT h = f2bf(v);
                            Ch[(size_t)gr * ldc + gc] = h;
                            Cl[(size_t)gr * ldc + gc] = f2bf(v - bf2f(h));
                        }
                    }
                }
            }
    }
}

// ---------------------------------------------------------------------------
// Copy x into f_g[:, 0:768] and into the x output region.
// ---------------------------------------------------------------------------
__global__ __launch_bounds__(256) void copy_x(const float* __restrict__ x,
                                              float* __restrict__ fg,
                                              float* __restrict__ xo) {
    size_t total = (size_t)NN * CD;
    for (size_t idx = (size_t)blockIdx.x * blockDim.x + threadIdx.x; idx < total;
         idx += (size_t)gridDim.x * blockDim.x) {
        size_t i = idx / CD, c = idx - i * CD;
        float v = x[idx];
        fg[i * FGD + c] = v;
        xo[idx] = v;
    }
}

// ---------------------------------------------------------------------------
// out[i] = f_g[i,:] . fcW + fcb
// ---------------------------------------------------------------------------
__global__ __launch_bounds__(256) void out_kernel(const float* __restrict__ fg,
                                                  const float* __restrict__ fcW,
                                                  const float* __restrict__ fcb,
                                                  float* __restrict__ out) {
    int i = blockIdx.x;
    float s = 0.0f;
    for (int j = threadIdx.x; j < FGD; j += 256)
        s += fg[(size_t)i * FGD + j] * fcW[j];
    for (int off = 32; off; off >>= 1) s += __shfl_down(s, off);
    __shared__ float sw[4];
    int wid = threadIdx.x >> 6, lane = threadIdx.x & 63;
    if (lane == 0) sw[wid] = s;
    __syncthreads();
    if (threadIdx.x == 0) out[i] = sw[0] + sw[1] + sw[2] + sw[3] + fcb[0];
}

extern "C" void kernel_launch(void* const* d_in, const int* in_sizes, int n_in,
                              void* d_out, int out_size, void* d_ws, size_t ws_size,
                              hipStream_t stream) {
    const float* x = (const float*)d_in[0];
    const int* labels = (const int*)d_in[1];
    const float* W1 = (const float*)d_in[2];
    const float* b1 = (const float*)d_in[3];
    const float* W2 = (const float*)d_in[4];
    const float* b2 = (const float*)d_in[5];
    const float* fcW = (const float*)d_in[6];
    const float* fcb = (const float*)d_in[7];
    float* outp = (float*)d_out;

    const size_t o_out = 0;
    const size_t o_fg = 4096;
    const size_t o_lm = o_fg + (size_t)NN * FGD;
    const size_t o_x = o_lm + (size_t)NN * NN;

    // workspace layout
    char* ws = (char*)d_ws;
    size_t off = 0;
    double* sim = (double*)(ws + off); off += (size_t)NN * NN * 8;      // 128 MiB
    ushortT* ab = (ushortT*)(ws + off); off += (size_t)NN * NN * 2;     // 32 MiB
    ushortT* xh = (ushortT*)(ws + off); off += (size_t)NN * CD * 2;
    ushortT* xl = (ushortT*)(ws + off); off += (size_t)NN * CD * 2;
    ushortT* w1th = (ushortT*)(ws + off); off += (size_t)HD * CD * 2;
    ushortT* w1tl = (ushortT*)(ws + off); off += (size_t)HD * CD * 2;
    ushortT* xw1sTh = (ushortT*)(ws + off); off += (size_t)HD * NN * 2;
    ushortT* xw1sTl = (ushortT*)(ws + off); off += (size_t)HD * NN * 2;
    ushortT* hh = (ushortT*)(ws + off); off += (size_t)NN * HD * 2;
    ushortT* hl = (ushortT*)(ws + off); off += (size_t)NN * HD * 2;
    ushortT* w2th = (ushortT*)(ws + off); off += (size_t)64 * HD * 2;
    ushortT* w2tl = (ushortT*)(ws + off); off += (size_t)64 * HD * 2;
    ushortT* hw2sTh = (ushortT*)(ws + off); off += (size_t)64 * NN * 2;
    ushortT* hw2sTl = (ushortT*)(ws + off); off += (size_t)64 * NN * 2;
    int* deg = (int*)(ws + off); off += (size_t)NN * 4;
    float* dinv = (float*)(ws + off); off += (size_t)NN * 4;
    double* scal = (double*)(ws + off); off += 16;

    hipMemsetAsync(scal, 0, 2 * sizeof(double), stream);

    // K1: sim = x @ x^T (fp64 MFMA)
    sim_mfma<<<dim3(64, 64), 256, 0, stream>>>(x, sim);

    // K2: threshold sums
    thr_reduce<<<2048, 256, 0, stream>>>(sim, labels, scal);

    // K3: mask + bf16 adjacency + degrees
    mask_kernel<<<NN, 256, 0, stream>>>(sim, labels, scal, ab, outp + o_lm, deg);
    dinv_kernel<<<(NN + 255) / 256, 256, 0, stream>>>(deg, dinv);

    // operand prep
    split_rm<<<4096, 256, 0, stream>>>(x, xh, xl, (size_t)NN * CD);
    transp_split<<<dim3(CD / 32, HD / 32), 256, 0, stream>>>(W1, w1th, w1tl, CD, HD, HD);
    transp_split<<<dim3(HD / 32, 2), 256, 0, stream>>>(W2, w2th, w2tl, HD, OD, 64);

    // K4: xw1sT = (dinv ⊙ (x @ W1))^T, split bf16   [M=4096,N=512,K=768]
    gemm_mfma<2, 2, true, false, false, 2><<<dim3(HD / 64, NN / 64), 256, 0, stream>>>(
        xh, xl, w1th, w1tl, nullptr, xw1sTh, xw1sTl, NN, HD, CD, 0, dinv, nullptr);

    // K5: h = relu(dinv ⊙ (a @ xw1s) + b1), split bf16 row-major  [K=4096]
    gemm_mfma<1, 2, false, true, true, 1><<<dim3(HD / 64, NN / 64), 256, 0, stream>>>(
        ab, nullptr, xw1sTh, xw1sTl, nullptr, hh, hl, NN, HD, NN, HD, dinv, b1);

    // K6: hw2sT = (dinv ⊙ (h @ W2))^T, split bf16   [N=50->64, K=512]
    gemm_mfma<2, 2, true, false, false, 2><<<dim3(1, NN / 64), 256, 0, stream>>>(
        hh, hl, w2th, w2tl, nullptr, hw2sTh, hw2sTl, NN, OD, HD, 0, dinv, nullptr);

    // K7: g = dinv ⊙ (a @ hw2s) + b2  -> f_g[:, 768:818] fp32   [K=4096]
    gemm_mfma<1, 2, false, false, true, 0><<<dim3(1, NN / 64), 256, 0, stream>>>(
        ab, nullptr, hw2sTh, hw2sTl, outp + o_fg + CD, nullptr, nullptr, NN, OD, NN,
        FGD, dinv, b2);

    copy_x<<<8192, 256, 0, stream>>>(x, outp + o_fg, outp + o_x);

    out_kernel<<<NN, 256, 0, stream>>>(outp + o_fg, fcW, fcb, outp + o_out);
}